// Round 1
// baseline (5473.199 us; speedup 1.0000x reference)
//
#include <hip/hip_runtime.h>
#include <hip/hip_bf16.h>

#define NNODES 50000
#define NEDGES 100000
#define INF 32
#define HID 32
#define KDIM 1024  // HID*INF

__device__ __forceinline__ float bf2f(unsigned short u) {
    union { unsigned int i; float f; } v; v.i = ((unsigned int)u) << 16; return v.f;
}
__device__ __forceinline__ unsigned short f2bf(float f) {
    union { unsigned int i; float f; } v; v.f = f;
    unsigned int r = v.i + 0x7FFFu + ((v.i >> 16) & 1u);  // round-to-nearest-even
    return (unsigned short)(r >> 16);
}

// ---------------------------------------------------------------------------
// Kernel 1: per-32-edge block: h1 = relu(ef@W1+b1) -> LDS(bf16);
// w = h1@W2+b2 (register-tiled, folded on the fly into msg = x_src . w);
// atomicAdd msg into agg[dst], deg[dst] += 1.
// ---------------------------------------------------------------------------
__global__ __launch_bounds__(256, 2) void k_edge_msg(
    const float* __restrict__ nf, const float* __restrict__ ef,
    const int* __restrict__ src, const int* __restrict__ dst,
    const float* __restrict__ W1, const float* __restrict__ b1,
    const float* __restrict__ W2, const float* __restrict__ b2,
    float* __restrict__ agg, float* __restrict__ deg)
{
    __shared__ __align__(16) unsigned short s_h1[KDIM * 32];  // [k][e], 64KB
    __shared__ float s_x[32][33];                              // [e][i], padded

    const int t  = threadIdx.x;
    const int e0 = blockIdx.x * 32;

    // ---- gather x = nf[src[e]] into LDS (32 edges x 32 feats) ----
    {
        const int ee = t >> 3, p = (t & 7) << 2;
        const int s = src[e0 + ee];
        const float4 xv = *(const float4*)(nf + (size_t)s * INF + p);
        s_x[ee][p + 0] = xv.x; s_x[ee][p + 1] = xv.y;
        s_x[ee][p + 2] = xv.z; s_x[ee][p + 3] = xv.w;
    }

    // ---- h1 phase: thread = (e = t&31, kk = t>>5); 4 consecutive k per step ----
    {
        const int e = t & 31, kk = t >> 5;
        float efr[32];
        #pragma unroll
        for (int q = 0; q < 8; ++q) {
            const float4 v = *(const float4*)(ef + (size_t)(e0 + e) * 32 + q * 4);
            efr[q * 4 + 0] = v.x; efr[q * 4 + 1] = v.y;
            efr[q * 4 + 2] = v.z; efr[q * 4 + 3] = v.w;
        }
        for (int m = 0; m < 32; ++m) {
            const int k0 = m * 32 + kk * 4;
            float4 acc = *(const float4*)(b1 + k0);
            #pragma unroll
            for (int f = 0; f < 32; ++f) {
                const float4 w = *(const float4*)(W1 + f * KDIM + k0);
                acc.x = fmaf(efr[f], w.x, acc.x);
                acc.y = fmaf(efr[f], w.y, acc.y);
                acc.z = fmaf(efr[f], w.z, acc.z);
                acc.w = fmaf(efr[f], w.w, acc.w);
            }
            s_h1[(k0 + 0) * 32 + e] = f2bf(fmaxf(acc.x, 0.f));
            s_h1[(k0 + 1) * 32 + e] = f2bf(fmaxf(acc.y, 0.f));
            s_h1[(k0 + 2) * 32 + e] = f2bf(fmaxf(acc.z, 0.f));
            s_h1[(k0 + 3) * 32 + e] = f2bf(fmaxf(acc.w, 0.f));
        }
    }
    __syncthreads();

    // ---- main GEMM: thread owns 4 edges (eg) x 8 cols (jg), 4 j-chunks of 256 ----
    const int jg = t & 31;          // 32 j-groups * 8 j = 256 cols per chunk
    const int eg = t >> 5;          // 8 e-groups * 4 e = 32 edges
    const int oc = (jg & 3) * 8;    // output-feat base: o = oc + b

    float pmsg[4][8];
    #pragma unroll
    for (int a = 0; a < 4; ++a)
        #pragma unroll
        for (int b = 0; b < 8; ++b) pmsg[a][b] = 0.f;

    for (int jc = 0; jc < 4; ++jc) {
        const int j0 = jc * 256 + jg * 8;
        float acc[4][8];
        #pragma unroll
        for (int a = 0; a < 4; ++a)
            #pragma unroll
            for (int b = 0; b < 8; ++b) acc[a][b] = 0.f;

        const float* w2row = W2 + j0;
        #pragma unroll 2
        for (int k = 0; k < KDIM; ++k) {
            const ushort4 hu = *(const ushort4*)(s_h1 + k * 32 + eg * 4);
            const float4 wa = *(const float4*)(w2row);
            const float4 wb = *(const float4*)(w2row + 4);
            w2row += KDIM;
            const float hv[4] = { bf2f(hu.x), bf2f(hu.y), bf2f(hu.z), bf2f(hu.w) };
            #pragma unroll
            for (int a = 0; a < 4; ++a) {
                acc[a][0] = fmaf(hv[a], wa.x, acc[a][0]);
                acc[a][1] = fmaf(hv[a], wa.y, acc[a][1]);
                acc[a][2] = fmaf(hv[a], wa.z, acc[a][2]);
                acc[a][3] = fmaf(hv[a], wa.w, acc[a][3]);
                acc[a][4] = fmaf(hv[a], wb.x, acc[a][4]);
                acc[a][5] = fmaf(hv[a], wb.y, acc[a][5]);
                acc[a][6] = fmaf(hv[a], wb.z, acc[a][6]);
                acc[a][7] = fmaf(hv[a], wb.w, acc[a][7]);
            }
        }
        // fold chunk into msg: j = j0+b -> (i = jc*8 + (jg>>2), o = oc+b)
        const float4 b2a = *(const float4*)(b2 + j0);
        const float4 b2b = *(const float4*)(b2 + j0 + 4);
        const int i = jc * 8 + (jg >> 2);
        #pragma unroll
        for (int a = 0; a < 4; ++a) {
            const float xv = s_x[eg * 4 + a][i];
            pmsg[a][0] = fmaf(xv, acc[a][0] + b2a.x, pmsg[a][0]);
            pmsg[a][1] = fmaf(xv, acc[a][1] + b2a.y, pmsg[a][1]);
            pmsg[a][2] = fmaf(xv, acc[a][2] + b2a.z, pmsg[a][2]);
            pmsg[a][3] = fmaf(xv, acc[a][3] + b2a.w, pmsg[a][3]);
            pmsg[a][4] = fmaf(xv, acc[a][4] + b2b.x, pmsg[a][4]);
            pmsg[a][5] = fmaf(xv, acc[a][5] + b2b.y, pmsg[a][5]);
            pmsg[a][6] = fmaf(xv, acc[a][6] + b2b.z, pmsg[a][6]);
            pmsg[a][7] = fmaf(xv, acc[a][7] + b2b.w, pmsg[a][7]);
        }
    }

    // ---- reduce over the 8 i-groups (lanes differing in jg bits 2..4) ----
    #pragma unroll
    for (int a = 0; a < 4; ++a)
        #pragma unroll
        for (int b = 0; b < 8; ++b) {
            pmsg[a][b] += __shfl_xor(pmsg[a][b], 4);
            pmsg[a][b] += __shfl_xor(pmsg[a][b], 8);
            pmsg[a][b] += __shfl_xor(pmsg[a][b], 16);
        }

    if ((jg >> 2) == 0) {
        #pragma unroll
        for (int a = 0; a < 4; ++a) {
            const int d = dst[e0 + eg * 4 + a];
            #pragma unroll
            for (int b = 0; b < 8; ++b)
                atomicAdd(&agg[(size_t)d * HID + oc + b], pmsg[a][b]);
        }
    }
    if (t < 32) atomicAdd(&deg[dst[e0 + t]], 1.0f);
}

// ---------------------------------------------------------------------------
// Kernel 2: h[n,o] = relu(agg[n,o]/max(deg,1) + bias[o])
// ---------------------------------------------------------------------------
__global__ __launch_bounds__(256) void k_node(
    const float* __restrict__ agg, const float* __restrict__ deg,
    const float* __restrict__ cbias, float* __restrict__ h)
{
    const int idx = blockIdx.x * 256 + threadIdx.x;
    if (idx >= NNODES * HID) return;
    const int n = idx >> 5, o = idx & 31;
    const float d = fmaxf(deg[n], 1.0f);
    h[idx] = fmaxf(agg[idx] / d + cbias[o], 0.0f);
}

// ---------------------------------------------------------------------------
// Kernel 3: logits = relu(concat(h[s],h[d],ef) @ Wc1 + bc1) @ Wc2 + bc2
// 8 edges/block, 32 lanes per edge (one per hidden unit).
// ---------------------------------------------------------------------------
__global__ __launch_bounds__(256) void k_cls(
    const float* __restrict__ h, const float* __restrict__ ef,
    const int* __restrict__ src, const int* __restrict__ dst,
    const int* __restrict__ eidx,
    const float* __restrict__ Wc1, const float* __restrict__ bc1,
    const float* __restrict__ Wc2, const float* __restrict__ bc2,
    float* __restrict__ out)
{
    __shared__ float s_w1[96 * 32];
    __shared__ float s_w2[96];
    __shared__ float s_b1[32];
    __shared__ float s_in[8][96];

    const int t = threadIdx.x;
    #pragma unroll
    for (int q = 0; q < 3; ++q)
        *(float4*)&s_w1[t * 12 + q * 4] = *(const float4*)&Wc1[t * 12 + q * 4];
    if (t < 96) s_w2[t] = Wc2[t];
    if (t >= 96 && t < 128) s_b1[t - 96] = bc1[t - 96];

    const int ee = t >> 5, l = t & 31;
    const int e = blockIdx.x * 8 + ee;
    const int ei = eidx[e];
    const int s = src[ei], d = dst[ei];
    s_in[ee][l]      = h[(size_t)s * HID + l];
    s_in[ee][32 + l] = h[(size_t)d * HID + l];
    s_in[ee][64 + l] = ef[(size_t)ei * 32 + l];
    __syncthreads();

    float acc = s_b1[l];
    #pragma unroll
    for (int c = 0; c < 96; ++c) acc = fmaf(s_in[ee][c], s_w1[c * 32 + l], acc);
    acc = fmaxf(acc, 0.f);

    float p0 = acc * s_w2[l * 3 + 0];
    float p1 = acc * s_w2[l * 3 + 1];
    float p2 = acc * s_w2[l * 3 + 2];
    #pragma unroll
    for (int m = 1; m <= 16; m <<= 1) {
        p0 += __shfl_xor(p0, m);
        p1 += __shfl_xor(p1, m);
        p2 += __shfl_xor(p2, m);
    }
    if (l == 0) {
        out[(size_t)e * 3 + 0] = p0 + bc2[0];
        out[(size_t)e * 3 + 1] = p1 + bc2[1];
        out[(size_t)e * 3 + 2] = p2 + bc2[2];
    }
}

extern "C" void kernel_launch(void* const* d_in, const int* in_sizes, int n_in,
                              void* d_out, int out_size, void* d_ws, size_t ws_size,
                              hipStream_t stream) {
    const float* nf   = (const float*)d_in[0];
    const float* ef   = (const float*)d_in[1];
    const int*   src  = (const int*)d_in[2];
    const int*   dst  = (const int*)d_in[3];
    const int*   eidx = (const int*)d_in[4];
    const float* W1   = (const float*)d_in[5];
    const float* b1   = (const float*)d_in[6];
    const float* W2   = (const float*)d_in[7];
    const float* b2   = (const float*)d_in[8];
    const float* cb   = (const float*)d_in[9];
    const float* Wc1  = (const float*)d_in[10];
    const float* bc1  = (const float*)d_in[11];
    const float* Wc2  = (const float*)d_in[12];
    const float* bc2  = (const float*)d_in[13];
    float* out = (float*)d_out;

    float* agg = (float*)d_ws;                 // NNODES*HID
    float* deg = agg + (size_t)NNODES * HID;   // NNODES
    float* h   = deg + NNODES;                 // NNODES*HID

    // agg + deg must be zero every call (atomics accumulate otherwise)
    hipMemsetAsync(d_ws, 0, ((size_t)NNODES * HID + NNODES) * sizeof(float), stream);

    k_edge_msg<<<NEDGES / 32, 256, 0, stream>>>(nf, ef, src, dst, W1, b1, W2, b2, agg, deg);
    k_node<<<(NNODES * HID + 255) / 256, 256, 0, stream>>>(agg, deg, cb, h);
    k_cls<<<NEDGES / 8, 256, 0, stream>>>(h, ef, src, dst, eidx, Wc1, bc1, Wc2, bc2, out);
}

// Round 2
// 1460.336 us; speedup vs baseline: 3.7479x; 3.7479x over previous
//
#include <hip/hip_runtime.h>
#include <hip/hip_bf16.h>
#include <stdint.h>

#define NNODES 50000
#define NEDGES 100000

typedef __attribute__((ext_vector_type(8))) short short8;
typedef __attribute__((ext_vector_type(4))) float f32x4;

__device__ __forceinline__ float bf2f(unsigned short u) {
    union { unsigned int i; float f; } v; v.i = ((unsigned int)u) << 16; return v.f;
}
__device__ __forceinline__ unsigned short f2bf(float f) {
    union { unsigned int i; float f; } v; v.f = f;
    unsigned int r = v.i + 0x7FFFu + ((v.i >> 16) & 1u);  // RNE
    return (unsigned short)(r >> 16);
}
__device__ __forceinline__ void gload16(const void* g, void* lds) {
    __builtin_amdgcn_global_load_lds(
        (const __attribute__((address_space(1))) unsigned int*)g,
        (__attribute__((address_space(3))) unsigned int*)lds, 16, 0, 0);
}

// ---------------------------------------------------------------------------
// Pack W2 (fp32 [1024][1024]) into bf16 B-fragment panels:
// w2p[(((nblk*32 + ks)*4 + kg)*128 + n)*8 + j] = W2[(ks*32+kg*8+j)][nblk*128+n]
// ---------------------------------------------------------------------------
__global__ __launch_bounds__(256) void k_pack(const float* __restrict__ W2,
                                              unsigned short* __restrict__ w2p) {
    const int c = blockIdx.x * 256 + threadIdx.x;      // 131072 chunks of 16B
    const int n   = c & 127;
    const int kg  = (c >> 7) & 3;
    const int ks  = (c >> 9) & 31;
    const int nb  = c >> 14;
    const int k0  = ks * 32 + kg * 8;
    const int col = nb * 128 + n;
    unsigned short o[8];
    #pragma unroll
    for (int j = 0; j < 8; ++j) o[j] = f2bf(W2[(size_t)(k0 + j) * 1024 + col]);
    uint4 pk;
    pk.x = o[0] | ((unsigned)o[1] << 16); pk.y = o[2] | ((unsigned)o[3] << 16);
    pk.z = o[4] | ((unsigned)o[5] << 16); pk.w = o[6] | ((unsigned)o[7] << 16);
    *(uint4*)(w2p + (size_t)c * 8) = pk;
}

__global__ __launch_bounds__(256) void k_deg(const int* __restrict__ dst,
                                             float* __restrict__ deg) {
    const int e = blockIdx.x * 256 + threadIdx.x;
    if (e < NEDGES) atomicAdd(&deg[dst[e]], 1.0f);
}

// ---------------------------------------------------------------------------
// h1 = relu(ef@W1 + b1), bf16, written in A-fragment panel layout (chunk-local):
// h1p[eblk*131072 + (k>>3)*1024 + (e&127)*8 + (k&7)]
// ---------------------------------------------------------------------------
__global__ __launch_bounds__(256) void k_h1(
    const float* __restrict__ ef, const float* __restrict__ W1,
    const float* __restrict__ b1, unsigned short* __restrict__ h1p, int r0)
{
    const int t  = threadIdx.x;
    const int e  = t & 31, kk = t >> 5;
    const int ec = blockIdx.x * 32 + e;   // chunk-local row
    const int eg = r0 + ec;               // global edge id
    const int eblk = ec >> 7, el = ec & 127;
    unsigned short* base = h1p + (size_t)eblk * 131072 + el * 8 + (kk & 1) * 4;
    const bool valid = eg < NEDGES;

    float efr[32];
    #pragma unroll
    for (int q = 0; q < 8; ++q) {
        float4 v = valid ? *(const float4*)(ef + (size_t)eg * 32 + q * 4)
                         : float4{0.f, 0.f, 0.f, 0.f};
        efr[q*4+0] = v.x; efr[q*4+1] = v.y; efr[q*4+2] = v.z; efr[q*4+3] = v.w;
    }
    for (int m = 0; m < 32; ++m) {
        const int k0 = m * 32 + kk * 4;
        float4 acc = *(const float4*)(b1 + k0);
        #pragma unroll
        for (int f = 0; f < 32; ++f) {
            const float4 w = *(const float4*)(W1 + f * 1024 + k0);
            acc.x = fmaf(efr[f], w.x, acc.x);
            acc.y = fmaf(efr[f], w.y, acc.y);
            acc.z = fmaf(efr[f], w.z, acc.z);
            acc.w = fmaf(efr[f], w.w, acc.w);
        }
        ushort4 o;
        o.x = valid ? f2bf(fmaxf(acc.x, 0.f)) : (unsigned short)0;
        o.y = valid ? f2bf(fmaxf(acc.y, 0.f)) : (unsigned short)0;
        o.z = valid ? f2bf(fmaxf(acc.z, 0.f)) : (unsigned short)0;
        o.w = valid ? f2bf(fmaxf(acc.w, 0.f)) : (unsigned short)0;
        *(ushort4*)(base + (size_t)(m * 4 + (kk >> 1)) * 1024) = o;
    }
}

// ---------------------------------------------------------------------------
// MFMA GEMM w = h1@W2 (+b2) fused with fold msg[e,o] = sum_i x[e,i]*w[e,32i+o]
// and atomic scatter into agg[dst]. 128 edges x (2 x 128 cols) per block.
// ---------------------------------------------------------------------------
__global__ __launch_bounds__(256) void k_gemm(
    const unsigned short* __restrict__ h1p, const unsigned short* __restrict__ w2p,
    const float* __restrict__ nf, const float* __restrict__ b2,
    const int* __restrict__ src, const int* __restrict__ dst,
    int r0, float* __restrict__ agg)
{
    __shared__ unsigned short sA[2][4096];   // 8KB x2, panel: [kg][128 rows][8k]
    __shared__ unsigned short sB[2][4096];
    __shared__ unsigned short sX[128][32];   // gathered src feats, bf16

    const int t    = threadIdx.x;
    const int lane = t & 63;
    const int wid  = t >> 6;
    const int wm   = wid & 1, wn = wid >> 1;   // 2x2 wave grid, 64x64 wave tile
    const int lq   = lane >> 4, lr = lane & 15;
    const int mblk = blockIdx.x, nsup = blockIdx.y;

    // gather x = nf[src[e]] -> bf16 LDS
    {
        const int e = t >> 1, fo = (t & 1) * 16;
        const int eg = r0 + mblk * 128 + e;
        if (eg < NEDGES) {
            const float* xp = nf + (size_t)src[eg] * 32 + fo;
            #pragma unroll
            for (int q = 0; q < 4; ++q) {
                float4 v = *(const float4*)(xp + q * 4);
                sX[e][fo + q*4 + 0] = f2bf(v.x);
                sX[e][fo + q*4 + 1] = f2bf(v.y);
                sX[e][fo + q*4 + 2] = f2bf(v.z);
                sX[e][fo + q*4 + 3] = f2bf(v.w);
            }
        } else {
            #pragma unroll
            for (int q = 0; q < 16; ++q) sX[e][fo + q] = 0;
        }
    }

    const unsigned short* gA = h1p + (size_t)mblk * 131072;
    float pm[32];                                  // [o-half 2][mt 4][r 4]
    #pragma unroll
    for (int i = 0; i < 32; ++i) pm[i] = 0.f;

    #define STAGE(dstb, gbase, ksrc) do {                                     \
        const unsigned short* _g = (gbase) + (size_t)(ksrc) * 4096;           \
        gload16(_g + (size_t)t * 8,         &(dstb)[(wid * 64) * 8]);         \
        gload16(_g + (size_t)(t + 256) * 8, &(dstb)[(256 + wid * 64) * 8]);   \
    } while (0)

    int buf = 0;
    for (int h = 0; h < 2; ++h) {
        const int nblk = nsup * 2 + h;
        const unsigned short* gB = w2p + (size_t)nblk * 131072;
        f32x4 acc[16];
        #pragma unroll
        for (int i = 0; i < 16; ++i) acc[i] = f32x4{0.f, 0.f, 0.f, 0.f};

        STAGE(sA[buf], gA, 0);
        STAGE(sB[buf], gB, 0);
        for (int ks = 0; ks < 32; ++ks) {
            __syncthreads();
            if (ks + 1 < 32) {
                STAGE(sA[buf ^ 1], gA, ks + 1);
                STAGE(sB[buf ^ 1], gB, ks + 1);
            }
            const unsigned short* pa = sA[buf];
            const unsigned short* pb = sB[buf];
            const int abase = (lq * 128 + wm * 64 + lr) * 8;
            const int bbase = (lq * 128 + wn * 64 + lr) * 8;
            short8 af[4], bfr[4];
            #pragma unroll
            for (int mt = 0; mt < 4; ++mt) af[mt]  = *(const short8*)(pa + abase + mt * 128);
            #pragma unroll
            for (int nt = 0; nt < 4; ++nt) bfr[nt] = *(const short8*)(pb + bbase + nt * 128);
            #pragma unroll
            for (int mt = 0; mt < 4; ++mt)
                #pragma unroll
                for (int nt = 0; nt < 4; ++nt)
                    acc[mt*4+nt] = __builtin_amdgcn_mfma_f32_16x16x32_bf16(
                        af[mt], bfr[nt], acc[mt*4+nt], 0, 0, 0);
            buf ^= 1;
        }
        // fold this n-half into pm
        #pragma unroll
        for (int nt = 0; nt < 4; ++nt) {
            const int i   = nblk * 4 + wn * 2 + (nt >> 1);
            const float bv = b2[nblk * 128 + wn * 64 + nt * 16 + lr];
            #pragma unroll
            for (int mt = 0; mt < 4; ++mt) {
                const int e = wm * 64 + mt * 16 + lq * 4;
                #pragma unroll
                for (int r = 0; r < 4; ++r) {
                    const float xv = bf2f(sX[e + r][i]);
                    if (nt & 1) pm[16 + mt*4 + r] = fmaf(xv, acc[mt*4+nt][r] + bv, pm[16 + mt*4 + r]);
                    else        pm[     mt*4 + r] = fmaf(xv, acc[mt*4+nt][r] + bv, pm[     mt*4 + r]);
                }
            }
        }
    }
    #undef STAGE

    // cross-wave (wn) reduce via LDS (alias sA, now dead), then atomic scatter
    __syncthreads();
    float* s_msg = (float*)sA;   // 128 x 32 fp32 = 16 KB
    if (wn == 0) {
        #pragma unroll
        for (int mt = 0; mt < 4; ++mt)
            #pragma unroll
            for (int r = 0; r < 4; ++r) {
                const int e = wm * 64 + mt * 16 + lq * 4 + r;
                s_msg[e * 32 + lr]      = pm[mt*4 + r];
                s_msg[e * 32 + 16 + lr] = pm[16 + mt*4 + r];
            }
    }
    __syncthreads();
    if (wn == 1) {
        #pragma unroll
        for (int mt = 0; mt < 4; ++mt)
            #pragma unroll
            for (int r = 0; r < 4; ++r) {
                const int e = wm * 64 + mt * 16 + lq * 4 + r;
                s_msg[e * 32 + lr]      += pm[mt*4 + r];
                s_msg[e * 32 + 16 + lr] += pm[16 + mt*4 + r];
            }
    }
    __syncthreads();
    {
        const int e = t >> 1, o0 = (t & 1) * 16;
        const int eg = r0 + mblk * 128 + e;
        if (eg < NEDGES) {
            float* ap = agg + (size_t)dst[eg] * 32 + o0;
            #pragma unroll
            for (int o = 0; o < 16; ++o) atomicAdd(ap + o, s_msg[e * 32 + o0 + o]);
        }
    }
}

// h[n,o] = relu(agg/max(deg,1) + bias) written in-place over agg
__global__ __launch_bounds__(256) void k_node(
    float* __restrict__ agg, const float* __restrict__ deg,
    const float* __restrict__ cbias)
{
    const int idx = blockIdx.x * 256 + threadIdx.x;
    if (idx >= NNODES * 32) return;
    const int n = idx >> 5, o = idx & 31;
    const float d = fmaxf(deg[n], 1.0f);
    agg[idx] = fmaxf(agg[idx] / d + cbias[o], 0.0f);
}

__global__ __launch_bounds__(256) void k_cls(
    const float* __restrict__ h, const float* __restrict__ ef,
    const int* __restrict__ src, const int* __restrict__ dst,
    const int* __restrict__ eidx,
    const float* __restrict__ Wc1, const float* __restrict__ bc1,
    const float* __restrict__ Wc2, const float* __restrict__ bc2,
    float* __restrict__ out)
{
    __shared__ float s_w1[96 * 32];
    __shared__ float s_w2[96];
    __shared__ float s_b1[32];
    __shared__ float s_in[8][96];

    const int t = threadIdx.x;
    #pragma unroll
    for (int q = 0; q < 3; ++q)
        *(float4*)&s_w1[t * 12 + q * 4] = *(const float4*)&Wc1[t * 12 + q * 4];
    if (t < 96) s_w2[t] = Wc2[t];
    if (t >= 96 && t < 128) s_b1[t - 96] = bc1[t - 96];

    const int ee = t >> 5, l = t & 31;
    const int e  = blockIdx.x * 8 + ee;
    const int ei = eidx[e];
    const int s = src[ei], d = dst[ei];
    s_in[ee][l]      = h[(size_t)s * 32 + l];
    s_in[ee][32 + l] = h[(size_t)d * 32 + l];
    s_in[ee][64 + l] = ef[(size_t)ei * 32 + l];
    __syncthreads();

    float acc = s_b1[l];
    #pragma unroll
    for (int c = 0; c < 96; ++c) acc = fmaf(s_in[ee][c], s_w1[c * 32 + l], acc);
    acc = fmaxf(acc, 0.f);

    float p0 = acc * s_w2[l * 3 + 0];
    float p1 = acc * s_w2[l * 3 + 1];
    float p2 = acc * s_w2[l * 3 + 2];
    #pragma unroll
    for (int m = 1; m <= 16; m <<= 1) {
        p0 += __shfl_xor(p0, m);
        p1 += __shfl_xor(p1, m);
        p2 += __shfl_xor(p2, m);
    }
    if (l == 0) {
        out[(size_t)e * 3 + 0] = p0 + bc2[0];
        out[(size_t)e * 3 + 1] = p1 + bc2[1];
        out[(size_t)e * 3 + 2] = p2 + bc2[2];
    }
}

extern "C" void kernel_launch(void* const* d_in, const int* in_sizes, int n_in,
                              void* d_out, int out_size, void* d_ws, size_t ws_size,
                              hipStream_t stream) {
    const float* nf   = (const float*)d_in[0];
    const float* ef   = (const float*)d_in[1];
    const int*   src  = (const int*)d_in[2];
    const int*   dst  = (const int*)d_in[3];
    const int*   eidx = (const int*)d_in[4];
    const float* W1   = (const float*)d_in[5];
    const float* b1   = (const float*)d_in[6];
    const float* W2   = (const float*)d_in[7];
    const float* b2   = (const float*)d_in[8];
    const float* cb   = (const float*)d_in[9];
    const float* Wc1  = (const float*)d_in[10];
    const float* bc1  = (const float*)d_in[11];
    const float* Wc2  = (const float*)d_in[12];
    const float* bc2  = (const float*)d_in[13];
    float* out = (float*)d_out;

    float* agg = (float*)d_ws;                               // 1,600,000 f32
    float* deg = agg + (size_t)NNODES * 32;                  // 50,000 f32
    unsigned short* w2p = (unsigned short*)(deg + NNODES);   // 1,048,576 bf16
    unsigned short* h1p = w2p + 1048576;                     // chunked

    const size_t fixed = ((size_t)NNODES * 32 + NNODES) * 4 + 1048576 * 2;
    const size_t avail = ws_size > fixed ? ws_size - fixed : 0;
    long long rpc = (long long)(avail / 2048);               // 2048 B per h1 row
    if (rpc > 100096) rpc = 100096;
    rpc &= ~127LL;
    if (rpc < 128) rpc = 128;

    hipMemsetAsync(d_ws, 0, ((size_t)NNODES * 32 + NNODES) * 4, stream);
    k_pack<<<512, 256, 0, stream>>>(W2, w2p);
    k_deg<<<(NEDGES + 255) / 256, 256, 0, stream>>>(dst, deg);

    for (long long r0 = 0; r0 < NEDGES; r0 += rpc) {
        long long rows = NEDGES - r0; if (rows > rpc) rows = rpc;
        const long long rowsPad = (rows + 127) & ~127LL;
        k_h1<<<(int)(rowsPad / 32), 256, 0, stream>>>(ef, W1, b1, h1p, (int)r0);
        k_gemm<<<dim3((int)(rowsPad / 128), 4), 256, 0, stream>>>(
            h1p, w2p, nf, b2, src, dst, (int)r0, agg);
    }

    k_node<<<(NNODES * 32 + 255) / 256, 256, 0, stream>>>(agg, deg, cb);
    k_cls<<<NEDGES / 8, 256, 0, stream>>>(agg, ef, src, dst, eidx, Wc1, bc1, Wc2, bc2, out);
}

// Round 3
// 491.076 us; speedup vs baseline: 11.1453x; 2.9737x over previous
//
#include <hip/hip_runtime.h>
#include <hip/hip_bf16.h>
#include <stdint.h>

#define NNODES 50000
#define NEDGES 100000

typedef __attribute__((ext_vector_type(8))) short short8;
typedef __attribute__((ext_vector_type(4))) float f32x4;

__device__ __forceinline__ unsigned short f2bf(float f) {
    union { unsigned int i; float f; } v; v.f = f;
    unsigned int r = v.i + 0x7FFFu + ((v.i >> 16) & 1u);  // RNE
    return (unsigned short)(r >> 16);
}
__device__ __forceinline__ void gload16(const void* g, void* lds) {
    __builtin_amdgcn_global_load_lds(
        (const __attribute__((address_space(1))) unsigned int*)g,
        (__attribute__((address_space(3))) unsigned int*)lds, 16, 0, 0);
}

// ---------------------------------------------------------------------------
// Pack W2 fp32[1024][1024] -> bf16 B-frag panels (coalesced reads):
// w2p[(((nb*32+ks)*4+kg)*128+n)*8+j] = W2[k][col], k=ks*32+kg*8+j, col=nb*128+n
// ---------------------------------------------------------------------------
__global__ __launch_bounds__(256) void k_pack(const float* __restrict__ W2,
                                              unsigned short* __restrict__ w2p) {
    const int idx = blockIdx.x * 256 + threadIdx.x;   // 1M elements
    const int k = idx >> 10, col = idx & 1023;
    const float v = W2[idx];
    const int nb = col >> 7, n = col & 127;
    const int ks = k >> 5, kg = (k >> 3) & 3, j = k & 7;
    w2p[((((size_t)nb * 32 + ks) * 4 + kg) * 128 + n) * 8 + j] = f2bf(v);
}

// ---------------------------------------------------------------------------
// Pack W1 fp32[32][1024] -> bf16 A-frag panels of W1^T (M = h1-col, K = ef-feat):
// w1pT[(((ks*2+kt)*4+lq)*16+lr)*8+ii] = W1[i][c], i=lq*8+ii, c=ks*32+kt*16+lr
// ---------------------------------------------------------------------------
__global__ __launch_bounds__(256) void k_packw1(const float* __restrict__ W1,
                                                unsigned short* __restrict__ w1pT) {
    const int idx = blockIdx.x * 256 + threadIdx.x;   // 32768 elements
    const int i = idx >> 10, col = idx & 1023;
    const float v = W1[idx];
    const int ks = col >> 5, c = col & 31;
    const int kt = c >> 4, lr = c & 15;
    const int lq = i >> 3, ii = i & 7;
    w1pT[((((size_t)ks * 2 + kt) * 4 + lq) * 16 + lr) * 8 + ii] = f2bf(v);
}

// ---------------------------------------------------------------------------
// Fully fused edge kernel: per 128-edge block (x), n-panel half (y):
//  h1 = relu(ef@W1+b1) produced per K-step via MFMA (wave-local, LDS-only),
//  w = h1@W2+b2 via MFMA (W2 staged from L2-resident packed panels),
//  msg fold + atomic scatter into agg[dst]; deg counted by y==0.
// ---------------------------------------------------------------------------
__global__ __launch_bounds__(256) void k_gemm(
    const unsigned short* __restrict__ w2p, const unsigned short* __restrict__ w1pT,
    const float* __restrict__ ef, const float* __restrict__ nf,
    const float* __restrict__ b1, const float* __restrict__ b2,
    const int* __restrict__ src, const int* __restrict__ dst,
    float* __restrict__ agg, float* __restrict__ deg)
{
    __shared__ __align__(16) unsigned short sE[4096];   // ef^T B-frag panel [iq4][e128][8]
    __shared__ __align__(16) unsigned short sH[4096];   // per-wave h1 A-frag slice [w][kq4][e32][8]
    __shared__ __align__(16) unsigned short sB[2][4096];// W2 panel double-buffer
    __shared__ float sX[128 * 36];                      // x = nf[src[e]] fp32, padded
    __shared__ int   sD[128];

    const int t    = threadIdx.x;
    const int lane = t & 63;
    const int w    = t >> 6;
    const int lq   = lane >> 4, lr = lane & 15;
    const int e0   = blockIdx.x * 128;
    const int yb   = blockIdx.y;

    // ---- phase 0: fill sE (bf16 ef panel), sX (fp32 gathered feats), sD ----
    {
        const int e = t >> 1, fo = (t & 1) * 16;
        const int eg = e0 + e;
        const bool valid = eg < NEDGES;
        float4 v[4];
        #pragma unroll
        for (int q = 0; q < 4; ++q)
            v[q] = valid ? *(const float4*)(ef + (size_t)eg * 32 + fo + q * 4)
                         : float4{0.f, 0.f, 0.f, 0.f};
        #pragma unroll
        for (int q = 0; q < 4; ++q) *(float4*)(sX + e * 36 + fo + q * 4) = v[q];

        unsigned short hh[16];
        #pragma unroll
        for (int q = 0; q < 4; ++q) {
            hh[q*4+0] = f2bf(v[q].x); hh[q*4+1] = f2bf(v[q].y);
            hh[q*4+2] = f2bf(v[q].z); hh[q*4+3] = f2bf(v[q].w);
        }
        uint4 pa, pb;
        pa.x = hh[0] | ((unsigned)hh[1] << 16);  pa.y = hh[2]  | ((unsigned)hh[3] << 16);
        pa.z = hh[4] | ((unsigned)hh[5] << 16);  pa.w = hh[6]  | ((unsigned)hh[7] << 16);
        pb.x = hh[8] | ((unsigned)hh[9] << 16);  pb.y = hh[10] | ((unsigned)hh[11] << 16);
        pb.z = hh[12]| ((unsigned)hh[13] << 16); pb.w = hh[14] | ((unsigned)hh[15] << 16);
        const int iq = fo >> 3;
        *(uint4*)(sE + ((iq    ) * 128 + e) * 8) = pa;
        *(uint4*)(sE + ((iq + 1) * 128 + e) * 8) = pb;

        // gather x
        const int s = valid ? src[eg] : 0;
        #pragma unroll
        for (int q = 0; q < 4; ++q) {
            float4 xv = valid ? *(const float4*)(nf + (size_t)s * 32 + fo + q * 4)
                              : float4{0.f, 0.f, 0.f, 0.f};
            *(float4*)(sX + e * 36 + fo + q * 4) = xv;
        }
    }
    // NOTE: sX was written twice above (ef then x) -- x is what must remain. OK.
    if (t < 128) {
        const int eg = e0 + t;
        const int dv = (eg < NEDGES) ? dst[eg] : -1;
        sD[t] = dv;
        if (yb == 0 && dv >= 0) atomicAdd(&deg[dv], 1.0f);
    }
    __syncthreads();

    // hoisted ef^T B-frags for this wave's 32 edges (invariant over ks, nblk)
    const short8 bfe0 = *(const short8*)(sE + (lq * 128 + w * 32      + lr) * 8);
    const short8 bfe1 = *(const short8*)(sE + (lq * 128 + w * 32 + 16 + lr) * 8);

    float pm[16];
    #pragma unroll
    for (int i = 0; i < 16; ++i) pm[i] = 0.f;

    #define STAGE(dstb, nblk_, ks_) do {                                        \
        const unsigned short* _g = w2p + (((size_t)(nblk_) * 32 + (ks_)) * 4096);\
        gload16(_g + (size_t)t * 8,         (dstb) + (w * 64) * 8);              \
        gload16(_g + (size_t)(t + 256) * 8, (dstb) + (256 + w * 64) * 8);        \
    } while (0)

    int buf = 0;
    STAGE(sB[0], yb * 4, 0);

    // register-prefetched W1 frags + b1 (ks-dependent only)
    short8 w1c0 = *(const short8*)(w1pT + (((0 * 2 + 0) * 4 + lq) * 16 + lr) * 8);
    short8 w1c1 = *(const short8*)(w1pT + (((0 * 2 + 1) * 4 + lq) * 16 + lr) * 8);
    float4 b1c0 = *(const float4*)(b1 + 0 * 32      + lq * 4);
    float4 b1c1 = *(const float4*)(b1 + 0 * 32 + 16 + lq * 4);

    for (int nb = 0; nb < 4; ++nb) {
        const int nblk = yb * 4 + nb;
        f32x4 acc[2][8];
        #pragma unroll
        for (int mt = 0; mt < 2; ++mt)
            #pragma unroll
            for (int nt = 0; nt < 8; ++nt) acc[mt][nt] = f32x4{0.f, 0.f, 0.f, 0.f};

        for (int ks = 0; ks < 32; ++ks) {
            __syncthreads();
            // stage next W2 panel
            {
                int nks = ks + 1, nnb = nblk;
                if (nks == 32) { nks = 0; nnb = nblk + 1; }
                if (!(nb == 3 && ks == 31)) STAGE(sB[buf ^ 1], nnb, nks);
            }
            // prefetch next W1 frags / b1 into fresh regs
            const int nks2 = (ks == 31) ? 0 : ks + 1;
            short8 w1n0 = *(const short8*)(w1pT + ((((size_t)nks2 * 2 + 0) * 4 + lq) * 16 + lr) * 8);
            short8 w1n1 = *(const short8*)(w1pT + ((((size_t)nks2 * 2 + 1) * 4 + lq) * 16 + lr) * 8);
            float4 b1n0 = *(const float4*)(b1 + nks2 * 32      + lq * 4);
            float4 b1n1 = *(const float4*)(b1 + nks2 * 32 + 16 + lq * 4);

            // ---- produce h1 slice: D[k=32][e=32] = W1^T-slice x ef^T  (+b1, relu) ----
            f32x4 h00 = {b1c0.x, b1c0.y, b1c0.z, b1c0.w};
            f32x4 h01 = h00;
            f32x4 h10 = {b1c1.x, b1c1.y, b1c1.z, b1c1.w};
            f32x4 h11 = h10;
            h00 = __builtin_amdgcn_mfma_f32_16x16x32_bf16(w1c0, bfe0, h00, 0, 0, 0);
            h01 = __builtin_amdgcn_mfma_f32_16x16x32_bf16(w1c0, bfe1, h01, 0, 0, 0);
            h10 = __builtin_amdgcn_mfma_f32_16x16x32_bf16(w1c1, bfe0, h10, 0, 0, 0);
            h11 = __builtin_amdgcn_mfma_f32_16x16x32_bf16(w1c1, bfe1, h11, 0, 0, 0);

            // relu + cvt_pk -> sH as A-frags (wave-local region, 4 consecutive k per lane)
            #define STORE_H1(hv, kt, et) do {                                          \
                float r0 = fmaxf((hv)[0], 0.f), r1 = fmaxf((hv)[1], 0.f);              \
                float r2 = fmaxf((hv)[2], 0.f), r3 = fmaxf((hv)[3], 0.f);              \
                unsigned p0, p1;                                                        \
                asm("v_cvt_pk_bf16_f32 %0, %1, %2" : "=v"(p0) : "v"(r0), "v"(r1));      \
                asm("v_cvt_pk_bf16_f32 %0, %1, %2" : "=v"(p1) : "v"(r2), "v"(r3));      \
                uint2 pk; pk.x = p0; pk.y = p1;                                         \
                *(uint2*)(sH + w * 1024 +                                               \
                    (((kt) * 2 + (lq >> 1)) * 32 + (et) * 16 + lr) * 8 + (lq & 1) * 4)  \
                    = pk;                                                               \
            } while (0)
            STORE_H1(h00, 0, 0); STORE_H1(h01, 0, 1);
            STORE_H1(h10, 1, 0); STORE_H1(h11, 1, 1);
            #undef STORE_H1

            // ---- main GEMM step: A = own h1 slice, B = staged W2 panel ----
            const unsigned short* pa = sH + w * 1024;
            const short8 af0 = *(const short8*)(pa + (lq * 32      + lr) * 8);
            const short8 af1 = *(const short8*)(pa + (lq * 32 + 16 + lr) * 8);
            const unsigned short* pb = sB[buf];
            #pragma unroll
            for (int nt = 0; nt < 8; ++nt) {
                const short8 bf = *(const short8*)(pb + (lq * 128 + nt * 16 + lr) * 8);
                acc[0][nt] = __builtin_amdgcn_mfma_f32_16x16x32_bf16(af0, bf, acc[0][nt], 0, 0, 0);
                acc[1][nt] = __builtin_amdgcn_mfma_f32_16x16x32_bf16(af1, bf, acc[1][nt], 0, 0, 0);
            }
            buf ^= 1;
            w1c0 = w1n0; w1c1 = w1n1; b1c0 = b1n0; b1c1 = b1n1;
        }

        // ---- fold this n-panel into pm: msg += x[e,i] * (w + b2) ----
        #pragma unroll
        for (int nt = 0; nt < 8; ++nt) {
            const float b2v = b2[nblk * 128 + nt * 16 + lr];
            const int i    = nblk * 4 + (nt >> 1);
            const int half = nt & 1;
            #pragma unroll
            for (int mt = 0; mt < 2; ++mt)
                #pragma unroll
                for (int r = 0; r < 4; ++r) {
                    const float x = sX[(w * 32 + mt * 16 + lq * 4 + r) * 36 + i];
                    pm[(mt * 4 + r) * 2 + half] =
                        fmaf(x, acc[mt][nt][r] + b2v, pm[(mt * 4 + r) * 2 + half]);
                }
        }
    }
    #undef STAGE

    // ---- scatter into agg[dst] ----
    #pragma unroll
    for (int mt = 0; mt < 2; ++mt)
        #pragma unroll
        for (int r = 0; r < 4; ++r) {
            const int el = w * 32 + mt * 16 + lq * 4 + r;
            const int d  = sD[el];
            if (d >= 0) {
                atomicAdd(agg + (size_t)d * 32 + lr,      pm[(mt * 4 + r) * 2]);
                atomicAdd(agg + (size_t)d * 32 + 16 + lr, pm[(mt * 4 + r) * 2 + 1]);
            }
        }
}

// h[n,o] = relu(agg/max(deg,1) + bias), in place over agg
__global__ __launch_bounds__(256) void k_node(
    float* __restrict__ agg, const float* __restrict__ deg,
    const float* __restrict__ cbias)
{
    const int idx = blockIdx.x * 256 + threadIdx.x;
    if (idx >= NNODES * 32) return;
    const int n = idx >> 5, o = idx & 31;
    const float d = fmaxf(deg[n], 1.0f);
    agg[idx] = fmaxf(agg[idx] / d + cbias[o], 0.0f);
}

__global__ __launch_bounds__(256) void k_cls(
    const float* __restrict__ h, const float* __restrict__ ef,
    const int* __restrict__ src, const int* __restrict__ dst,
    const int* __restrict__ eidx,
    const float* __restrict__ Wc1, const float* __restrict__ bc1,
    const float* __restrict__ Wc2, const float* __restrict__ bc2,
    float* __restrict__ out)
{
    __shared__ float s_w1[96 * 32];
    __shared__ float s_w2[96];
    __shared__ float s_b1[32];
    __shared__ float s_in[8][96];

    const int t = threadIdx.x;
    #pragma unroll
    for (int q = 0; q < 3; ++q)
        *(float4*)&s_w1[t * 12 + q * 4] = *(const float4*)&Wc1[t * 12 + q * 4];
    if (t < 96) s_w2[t] = Wc2[t];
    if (t >= 96 && t < 128) s_b1[t - 96] = bc1[t - 96];

    const int ee = t >> 5, l = t & 31;
    const int e  = blockIdx.x * 8 + ee;
    const int ei = eidx[e];
    const int s = src[ei], d = dst[ei];
    s_in[ee][l]      = h[(size_t)s * 32 + l];
    s_in[ee][32 + l] = h[(size_t)d * 32 + l];
    s_in[ee][64 + l] = ef[(size_t)ei * 32 + l];
    __syncthreads();

    float acc = s_b1[l];
    #pragma unroll
    for (int c = 0; c < 96; ++c) acc = fmaf(s_in[ee][c], s_w1[c * 32 + l], acc);
    acc = fmaxf(acc, 0.f);

    float p0 = acc * s_w2[l * 3 + 0];
    float p1 = acc * s_w2[l * 3 + 1];
    float p2 = acc * s_w2[l * 3 + 2];
    #pragma unroll
    for (int m = 1; m <= 16; m <<= 1) {
        p0 += __shfl_xor(p0, m);
        p1 += __shfl_xor(p1, m);
        p2 += __shfl_xor(p2, m);
    }
    if (l == 0) {
        out[(size_t)e * 3 + 0] = p0 + bc2[0];
        out[(size_t)e * 3 + 1] = p1 + bc2[1];
        out[(size_t)e * 3 + 2] = p2 + bc2[2];
    }
}

extern "C" void kernel_launch(void* const* d_in, const int* in_sizes, int n_in,
                              void* d_out, int out_size, void* d_ws, size_t ws_size,
                              hipStream_t stream) {
    const float* nf   = (const float*)d_in[0];
    const float* ef   = (const float*)d_in[1];
    const int*   src  = (const int*)d_in[2];
    const int*   dst  = (const int*)d_in[3];
    const int*   eidx = (const int*)d_in[4];
    const float* W1   = (const float*)d_in[5];
    const float* b1   = (const float*)d_in[6];
    const float* W2   = (const float*)d_in[7];
    const float* b2   = (const float*)d_in[8];
    const float* cb   = (const float*)d_in[9];
    const float* Wc1  = (const float*)d_in[10];
    const float* bc1  = (const float*)d_in[11];
    const float* Wc2  = (const float*)d_in[12];
    const float* bc2  = (const float*)d_in[13];
    float* out = (float*)d_out;

    float* agg = (float*)d_ws;                               // 1,600,000 f32
    float* deg = agg + (size_t)NNODES * 32;                  // 50,000 f32
    unsigned short* w2p  = (unsigned short*)(deg + NNODES);  // 1,048,576 bf16
    unsigned short* w1pT = w2p + 1048576;                    // 32,768 bf16

    hipMemsetAsync(d_ws, 0, ((size_t)NNODES * 32 + NNODES) * 4, stream);
    k_pack<<<4096, 256, 0, stream>>>(W2, w2p);
    k_packw1<<<128, 256, 0, stream>>>(W1, w1pT);

    k_gemm<<<dim3((NEDGES + 127) / 128, 2), 256, 0, stream>>>(
        w2p, w1pT, ef, nf, b1, b2, src, dst, agg, deg);

    k_node<<<(NNODES * 32 + 255) / 256, 256, 0, stream>>>(agg, deg, cb);
    k_cls<<<NEDGES / 8, 256, 0, stream>>>(agg, ef, src, dst, eidx, Wc1, bc1, Wc2, bc2, out);
}

// Round 4
// 354.920 us; speedup vs baseline: 15.4209x; 1.3836x over previous
//
#include <hip/hip_runtime.h>
#include <hip/hip_bf16.h>
#include <stdint.h>

#define NNODES 50000
#define NEDGES 100000

typedef __attribute__((ext_vector_type(8))) short short8;
typedef __attribute__((ext_vector_type(4))) float f32x4;

__device__ __forceinline__ unsigned short f2bf(float f) {
    union { unsigned int i; float f; } v; v.f = f;
    unsigned int r = v.i + 0x7FFFu + ((v.i >> 16) & 1u);  // RNE
    return (unsigned short)(r >> 16);
}
__device__ __forceinline__ void gload16(const void* g, void* lds) {
    __builtin_amdgcn_global_load_lds(
        (const __attribute__((address_space(1))) unsigned int*)g,
        (__attribute__((address_space(3))) unsigned int*)lds, 16, 0, 0);
}

// ---------------------------------------------------------------------------
// Pack W2 fp32[1024][1024] -> bf16 B-frag panels (coalesced reads):
// w2p[(((nb*32+ks)*4+kg)*128+n)*8+j] = W2[k][col], k=ks*32+kg*8+j, col=nb*128+n
// ---------------------------------------------------------------------------
__global__ __launch_bounds__(256) void k_pack(const float* __restrict__ W2,
                                              unsigned short* __restrict__ w2p) {
    const int idx = blockIdx.x * 256 + threadIdx.x;   // 1M elements
    const int k = idx >> 10, col = idx & 1023;
    const float v = W2[idx];
    const int nb = col >> 7, n = col & 127;
    const int ks = k >> 5, kg = (k >> 3) & 3, j = k & 7;
    w2p[((((size_t)nb * 32 + ks) * 4 + kg) * 128 + n) * 8 + j] = f2bf(v);
}

// ---------------------------------------------------------------------------
// Pack W1 fp32[32][1024] -> bf16 A-frag panels of W1^T (M = h1-col, K = ef-feat):
// w1pT[(((ks*2+kt)*4+lq)*16+lr)*8+ii] = W1[i][c], i=lq*8+ii, c=ks*32+kt*16+lr
// ---------------------------------------------------------------------------
__global__ __launch_bounds__(256) void k_packw1(const float* __restrict__ W1,
                                                unsigned short* __restrict__ w1pT) {
    const int idx = blockIdx.x * 256 + threadIdx.x;   // 32768 elements
    const int i = idx >> 10, col = idx & 1023;
    const float v = W1[idx];
    const int ks = col >> 5, c = col & 31;
    const int kt = c >> 4, lr = c & 15;
    const int lq = i >> 3, ii = i & 7;
    w1pT[((((size_t)ks * 2 + kt) * 4 + lq) * 16 + lr) * 8 + ii] = f2bf(v);
}

// ---------------------------------------------------------------------------
// Fused edge kernel, 128 edges/block, 4 n-passes of 256 cols each:
//  h1 produced per K-step via MFMA (wave-local LDS round-trip),
//  w = h1@W2 via MFMA (2 W2 panels staged per K-step),
//  pm initialized by x(x)b2 MFMA, fold per pass, atomic scatter at end.
// ---------------------------------------------------------------------------
__global__ __launch_bounds__(256, 2) void k_gemm(
    const unsigned short* __restrict__ w2p, const unsigned short* __restrict__ w1pT,
    const float* __restrict__ ef, const float* __restrict__ nf,
    const float* __restrict__ b1, const float* __restrict__ b2,
    const int* __restrict__ src, const int* __restrict__ dst,
    float* __restrict__ agg, float* __restrict__ deg)
{
    __shared__ __align__(16) unsigned short sE[4096];    // ef^T B-frag panel  (8KB)
    __shared__ __align__(16) unsigned short sXb[4096];   // x A-frag panel bf16 (8KB)
    __shared__ __align__(16) unsigned short sH[4096];    // per-wave h1 A-frags (8KB)
    __shared__ __align__(16) unsigned short sB[2][8192]; // 2-panel W2 dbuf (32KB)
    __shared__ float sX[128 * 36];                       // fp32 x for fold (18KB)
    __shared__ int   sD[128];

    const int t    = threadIdx.x;
    const int lane = t & 63;
    const int w    = t >> 6;
    const int lq   = lane >> 4, lr = lane & 15;
    const int e0   = blockIdx.x * 128;

    // ---- phase 0: sE (ef B-frags), sX fp32 + sXb (x A-frags), sD ----
    {
        const int e = t >> 1, fo = (t & 1) * 16;
        const int eg = e0 + e;
        const bool valid = eg < NEDGES;
        const int iq = fo >> 3;

        // ef -> sE
        float4 v[4];
        #pragma unroll
        for (int q = 0; q < 4; ++q)
            v[q] = valid ? *(const float4*)(ef + (size_t)eg * 32 + fo + q * 4)
                         : float4{0.f, 0.f, 0.f, 0.f};
        unsigned short hh[16];
        #pragma unroll
        for (int q = 0; q < 4; ++q) {
            hh[q*4+0] = f2bf(v[q].x); hh[q*4+1] = f2bf(v[q].y);
            hh[q*4+2] = f2bf(v[q].z); hh[q*4+3] = f2bf(v[q].w);
        }
        uint4 pa, pb;
        pa.x = hh[0] | ((unsigned)hh[1] << 16);  pa.y = hh[2]  | ((unsigned)hh[3] << 16);
        pa.z = hh[4] | ((unsigned)hh[5] << 16);  pa.w = hh[6]  | ((unsigned)hh[7] << 16);
        pb.x = hh[8] | ((unsigned)hh[9] << 16);  pb.y = hh[10] | ((unsigned)hh[11] << 16);
        pb.z = hh[12]| ((unsigned)hh[13] << 16); pb.w = hh[14] | ((unsigned)hh[15] << 16);
        *(uint4*)(sE + ((iq    ) * 128 + e) * 8) = pa;
        *(uint4*)(sE + ((iq + 1) * 128 + e) * 8) = pb;

        // x = nf[src[e]] -> sX (fp32) + sXb (bf16 A-frags)
        const int s = valid ? src[eg] : 0;
        #pragma unroll
        for (int q = 0; q < 4; ++q) {
            float4 xv = valid ? *(const float4*)(nf + (size_t)s * 32 + fo + q * 4)
                              : float4{0.f, 0.f, 0.f, 0.f};
            *(float4*)(sX + e * 36 + fo + q * 4) = xv;
            hh[q*4+0] = f2bf(xv.x); hh[q*4+1] = f2bf(xv.y);
            hh[q*4+2] = f2bf(xv.z); hh[q*4+3] = f2bf(xv.w);
        }
        pa.x = hh[0] | ((unsigned)hh[1] << 16);  pa.y = hh[2]  | ((unsigned)hh[3] << 16);
        pa.z = hh[4] | ((unsigned)hh[5] << 16);  pa.w = hh[6]  | ((unsigned)hh[7] << 16);
        pb.x = hh[8] | ((unsigned)hh[9] << 16);  pb.y = hh[10] | ((unsigned)hh[11] << 16);
        pb.z = hh[12]| ((unsigned)hh[13] << 16); pb.w = hh[14] | ((unsigned)hh[15] << 16);
        *(uint4*)(sXb + ((iq    ) * 128 + e) * 8) = pa;
        *(uint4*)(sXb + ((iq + 1) * 128 + e) * 8) = pb;
    }
    if (t < 128) {
        const int eg = e0 + t;
        const int dv = (eg < NEDGES) ? dst[eg] : -1;
        sD[t] = dv;
        if (dv >= 0) atomicAdd(&deg[dv], 1.0f);
    }
    __syncthreads();

    // hoisted ef^T B-frags for this wave's 32 edges
    const short8 bfe0 = *(const short8*)(sE + (lq * 128 + w * 32      + lr) * 8);
    const short8 bfe1 = *(const short8*)(sE + (lq * 128 + w * 32 + 16 + lr) * 8);

    // ---- pm init: pm[e,o] = sum_i x[e,i]*b2[i*32+o] via 4 MFMAs ----
    f32x4 pm4[4];   // [et*2 + o-half], layout col=o=lr, row=e=lq*4+r
    {
        const short8 xf0 = *(const short8*)(sXb + (lq * 128 + w * 32      + lr) * 8);
        const short8 xf1 = *(const short8*)(sXb + (lq * 128 + w * 32 + 16 + lr) * 8);
        short8 bb0, bb1;
        #pragma unroll
        for (int j = 0; j < 8; ++j) {
            bb0[j] = (short)f2bf(b2[(lq * 8 + j) * 32 + lr]);
            bb1[j] = (short)f2bf(b2[(lq * 8 + j) * 32 + 16 + lr]);
        }
        const f32x4 z = {0.f, 0.f, 0.f, 0.f};
        pm4[0] = __builtin_amdgcn_mfma_f32_16x16x32_bf16(xf0, bb0, z, 0, 0, 0);
        pm4[1] = __builtin_amdgcn_mfma_f32_16x16x32_bf16(xf0, bb1, z, 0, 0, 0);
        pm4[2] = __builtin_amdgcn_mfma_f32_16x16x32_bf16(xf1, bb0, z, 0, 0, 0);
        pm4[3] = __builtin_amdgcn_mfma_f32_16x16x32_bf16(xf1, bb1, z, 0, 0, 0);
    }

    #define STAGE2(dstb, nblk_, ks_) do {                                          \
        const unsigned short* _g0 = w2p + ((size_t)((nblk_) * 32 + (ks_)) * 4096); \
        const unsigned short* _g1 = _g0 + (size_t)32 * 4096;                       \
        gload16(_g0 + (size_t)t * 8,         (dstb) + w * 512);                    \
        gload16(_g0 + (size_t)(t + 256) * 8, (dstb) + 2048 + w * 512);             \
        gload16(_g1 + (size_t)t * 8,         (dstb) + 4096 + w * 512);             \
        gload16(_g1 + (size_t)(t + 256) * 8, (dstb) + 6144 + w * 512);             \
    } while (0)

    int buf = 0;
    STAGE2(sB[0], 0, 0);

    // register-prefetched W1 frags + b1 (ks-dependent only)
    short8 w1c0 = *(const short8*)(w1pT + ((0 * 4 + lq) * 16 + lr) * 8);
    short8 w1c1 = *(const short8*)(w1pT + ((1 * 4 + lq) * 16 + lr) * 8);
    float4 b1c0 = *(const float4*)(b1 + lq * 4);
    float4 b1c1 = *(const float4*)(b1 + 16 + lq * 4);

    for (int nbp = 0; nbp < 4; ++nbp) {
        const int nblk0 = nbp * 2;
        f32x4 acc[2][16];
        #pragma unroll
        for (int mt = 0; mt < 2; ++mt)
            #pragma unroll
            for (int nt = 0; nt < 16; ++nt) acc[mt][nt] = f32x4{0.f, 0.f, 0.f, 0.f};

        for (int ks = 0; ks < 32; ++ks) {
            __syncthreads();
            // stage next 2-panel W2 slab
            {
                int nks = ks + 1, nnb = nblk0;
                if (nks == 32) { nks = 0; nnb = nblk0 + 2; }
                if (!(nbp == 3 && ks == 31)) STAGE2(sB[buf ^ 1], nnb, nks);
            }
            // prefetch next W1 frags / b1
            const int nks2 = (ks == 31) ? 0 : ks + 1;
            short8 w1n0 = *(const short8*)(w1pT + ((((size_t)nks2 * 2 + 0) * 4 + lq) * 16 + lr) * 8);
            short8 w1n1 = *(const short8*)(w1pT + ((((size_t)nks2 * 2 + 1) * 4 + lq) * 16 + lr) * 8);
            float4 b1n0 = *(const float4*)(b1 + nks2 * 32      + lq * 4);
            float4 b1n1 = *(const float4*)(b1 + nks2 * 32 + 16 + lq * 4);

            // ---- h1 slice: D[k=32][e=32] = W1^T x ef^T (+b1, relu) -> sH ----
            f32x4 h00 = {b1c0.x, b1c0.y, b1c0.z, b1c0.w};
            f32x4 h01 = h00;
            f32x4 h10 = {b1c1.x, b1c1.y, b1c1.z, b1c1.w};
            f32x4 h11 = h10;
            h00 = __builtin_amdgcn_mfma_f32_16x16x32_bf16(w1c0, bfe0, h00, 0, 0, 0);
            h01 = __builtin_amdgcn_mfma_f32_16x16x32_bf16(w1c0, bfe1, h01, 0, 0, 0);
            h10 = __builtin_amdgcn_mfma_f32_16x16x32_bf16(w1c1, bfe0, h10, 0, 0, 0);
            h11 = __builtin_amdgcn_mfma_f32_16x16x32_bf16(w1c1, bfe1, h11, 0, 0, 0);

            #define STORE_H1(hv, kt, et) do {                                          \
                float r0 = fmaxf((hv)[0], 0.f), r1 = fmaxf((hv)[1], 0.f);              \
                float r2 = fmaxf((hv)[2], 0.f), r3 = fmaxf((hv)[3], 0.f);              \
                unsigned p0, p1;                                                        \
                asm("v_cvt_pk_bf16_f32 %0, %1, %2" : "=v"(p0) : "v"(r0), "v"(r1));      \
                asm("v_cvt_pk_bf16_f32 %0, %1, %2" : "=v"(p1) : "v"(r2), "v"(r3));      \
                uint2 pk; pk.x = p0; pk.y = p1;                                         \
                *(uint2*)(sH + w * 1024 +                                               \
                    (((kt) * 2 + (lq >> 1)) * 32 + (et) * 16 + lr) * 8 + (lq & 1) * 4)  \
                    = pk;                                                               \
            } while (0)
            STORE_H1(h00, 0, 0); STORE_H1(h01, 0, 1);
            STORE_H1(h10, 1, 0); STORE_H1(h11, 1, 1);
            #undef STORE_H1

            // ---- main GEMM step: 32 MFMAs over 2 staged panels ----
            const unsigned short* pa = sH + w * 1024;
            const short8 af0 = *(const short8*)(pa + (lq * 32      + lr) * 8);
            const short8 af1 = *(const short8*)(pa + (lq * 32 + 16 + lr) * 8);
            const unsigned short* pb = sB[buf];
            #pragma unroll
            for (int np = 0; np < 2; ++np)
                #pragma unroll
                for (int nt = 0; nt < 8; ++nt) {
                    const short8 bf = *(const short8*)(pb + np * 4096 + (lq * 128 + nt * 16 + lr) * 8);
                    acc[0][np*8+nt] = __builtin_amdgcn_mfma_f32_16x16x32_bf16(af0, bf, acc[0][np*8+nt], 0, 0, 0);
                    acc[1][np*8+nt] = __builtin_amdgcn_mfma_f32_16x16x32_bf16(af1, bf, acc[1][np*8+nt], 0, 0, 0);
                }
            buf ^= 1;
            w1c0 = w1n0; w1c1 = w1n1; b1c0 = b1n0; b1c1 = b1n1;
        }

        // ---- fold: pm += x[e,i] * w  (b2 already folded via pm init) ----
        #pragma unroll
        for (int np = 0; np < 2; ++np) {
            const int nblk = nblk0 + np;
            #pragma unroll
            for (int nt = 0; nt < 8; ++nt) {
                const int i    = nblk * 4 + (nt >> 1);
                const int half = nt & 1;
                #pragma unroll
                for (int mt = 0; mt < 2; ++mt)
                    #pragma unroll
                    for (int r = 0; r < 4; ++r) {
                        const float x = sX[(w * 32 + mt * 16 + lq * 4 + r) * 36 + i];
                        pm4[mt * 2 + half][r] = fmaf(x, acc[mt][np*8+nt][r], pm4[mt * 2 + half][r]);
                    }
            }
        }
    }
    #undef STAGE2

    // ---- scatter into agg[dst] ----
    #pragma unroll
    for (int mt = 0; mt < 2; ++mt)
        #pragma unroll
        for (int r = 0; r < 4; ++r) {
            const int el = w * 32 + mt * 16 + lq * 4 + r;
            const int d  = sD[el];
            if (d >= 0) {
                atomicAdd(agg + (size_t)d * 32 + lr,      pm4[mt * 2][r]);
                atomicAdd(agg + (size_t)d * 32 + 16 + lr, pm4[mt * 2 + 1][r]);
            }
        }
}

// h[n,o] = relu(agg/max(deg,1) + bias), in place over agg
__global__ __launch_bounds__(256) void k_node(
    float* __restrict__ agg, const float* __restrict__ deg,
    const float* __restrict__ cbias)
{
    const int idx = blockIdx.x * 256 + threadIdx.x;
    if (idx >= NNODES * 32) return;
    const int n = idx >> 5, o = idx & 31;
    const float d = fmaxf(deg[n], 1.0f);
    agg[idx] = fmaxf(agg[idx] / d + cbias[o], 0.0f);
}

__global__ __launch_bounds__(256) void k_cls(
    const float* __restrict__ h, const float* __restrict__ ef,
    const int* __restrict__ src, const int* __restrict__ dst,
    const int* __restrict__ eidx,
    const float* __restrict__ Wc1, const float* __restrict__ bc1,
    const float* __restrict__ Wc2, const float* __restrict__ bc2,
    float* __restrict__ out)
{
    __shared__ float s_w1[96 * 32];
    __shared__ float s_w2[96];
    __shared__ float s_b1[32];
    __shared__ float s_in[8][96];

    const int t = threadIdx.x;
    #pragma unroll
    for (int q = 0; q < 3; ++q)
        *(float4*)&s_w1[t * 12 + q * 4] = *(const float4*)&Wc1[t * 12 + q * 4];
    if (t < 96) s_w2[t] = Wc2[t];
    if (t >= 96 && t < 128) s_b1[t - 96] = bc1[t - 96];

    const int ee = t >> 5, l = t & 31;
    const int e  = blockIdx.x * 8 + ee;
    const int ei = eidx[e];
    const int s = src[ei], d = dst[ei];
    s_in[ee][l]      = h[(size_t)s * 32 + l];
    s_in[ee][32 + l] = h[(size_t)d * 32 + l];
    s_in[ee][64 + l] = ef[(size_t)ei * 32 + l];
    __syncthreads();

    float acc = s_b1[l];
    #pragma unroll
    for (int c = 0; c < 96; ++c) acc = fmaf(s_in[ee][c], s_w1[c * 32 + l], acc);
    acc = fmaxf(acc, 0.f);

    float p0 = acc * s_w2[l * 3 + 0];
    float p1 = acc * s_w2[l * 3 + 1];
    float p2 = acc * s_w2[l * 3 + 2];
    #pragma unroll
    for (int m = 1; m <= 16; m <<= 1) {
        p0 += __shfl_xor(p0, m);
        p1 += __shfl_xor(p1, m);
        p2 += __shfl_xor(p2, m);
    }
    if (l == 0) {
        out[(size_t)e * 3 + 0] = p0 + bc2[0];
        out[(size_t)e * 3 + 1] = p1 + bc2[1];
        out[(size_t)e * 3 + 2] = p2 + bc2[2];
    }
}

extern "C" void kernel_launch(void* const* d_in, const int* in_sizes, int n_in,
                              void* d_out, int out_size, void* d_ws, size_t ws_size,
                              hipStream_t stream) {
    const float* nf   = (const float*)d_in[0];
    const float* ef   = (const float*)d_in[1];
    const int*   src  = (const int*)d_in[2];
    const int*   dst  = (const int*)d_in[3];
    const int*   eidx = (const int*)d_in[4];
    const float* W1   = (const float*)d_in[5];
    const float* b1   = (const float*)d_in[6];
    const float* W2   = (const float*)d_in[7];
    const float* b2   = (const float*)d_in[8];
    const float* cb   = (const float*)d_in[9];
    const float* Wc1  = (const float*)d_in[10];
    const float* bc1  = (const float*)d_in[11];
    const float* Wc2  = (const float*)d_in[12];
    const float* bc2  = (const float*)d_in[13];
    float* out = (float*)d_out;

    float* agg = (float*)d_ws;                               // 1,600,000 f32
    float* deg = agg + (size_t)NNODES * 32;                  // 50,000 f32
    unsigned short* w2p  = (unsigned short*)(deg + NNODES);  // 1,048,576 bf16
    unsigned short* w1pT = w2p + 1048576;                    // 32,768 bf16

    hipMemsetAsync(d_ws, 0, ((size_t)NNODES * 32 + NNODES) * 4, stream);
    k_pack<<<4096, 256, 0, stream>>>(W2, w2p);
    k_packw1<<<128, 256, 0, stream>>>(W1, w1pT);

    k_gemm<<<(NEDGES + 127) / 128, 256, 0, stream>>>(
        w2p, w1pT, ef, nf, b1, b2, src, dst, agg, deg);

    k_node<<<(NNODES * 32 + 255) / 256, 256, 0, stream>>>(agg, deg, cb);
    k_cls<<<NEDGES / 8, 256, 0, stream>>>(agg, ef, src, dst, eidx, Wc1, bc1, Wc2, bc2, out);
}